// Round 4
// baseline (238.602 us; speedup 1.0000x reference)
//
#include <hip/hip_runtime.h>

// Persistence-image kernel, MI355X — column-factorized, reg-headroom (R4).
// S=128, I=32 intervals, C=32 corners, R=30 -> G=900.
// img[s,g] = sum_i w_i^2 * exp(-200 * max(min_c |g-b_ic|^2, min_c |g-d_ic|^2))
// |g-p|^2 = (r_c + qx_c*gx + qy_c*gy) + |g|^2 with qx=-2px, qy=-2py, r=|p|^2.
//
// History: R2 (arrays, 10 rows) and R3 (named scalars, 5 rows, caps 85-128)
// both hit pathological scratch demotion: VGPR 36/40, 58-580MB scratch
// traffic, VALUBusy ~10%. Diagnosis: unrolled macro streams make the
// scheduler hoist LDS loads / software-pipeline, pushing PEAK reg demand past
// the launch_bounds cap -> allocator demotes the working set to scratch.
// R4 discipline: cap 128 VGPR vs ~60 needed (2x headroom), named scalars,
// 8 rows/thread (amortizes: per 4 corners = 3 broadcast ds_read_b128 + 68
// VALU -> 2.1 ops/eval, LDS pipe balanced with VALU), no early return.
// Block = (sample, interval-pair): 128 thr = 30 cols x 4 row-octets (+8 idle).
// Grid 2048 blocks x 2 waves = 4096 waves: co-resident at 4 waves/SIMD.

#define RES 30
#define GPTS 900
#define NS 128
#define NI 32
#define INV29 (1.0f / 29.0f)
#define WS_STRIDE 40  // floats per sample in ws: [0..3]=box lo/hi, [8..39]=w2[i]

__global__ __launch_bounds__(128) void prep_kernel(
    const float* __restrict__ births, const float* __restrict__ deaths,
    float* __restrict__ out, float* __restrict__ ws)
{
    const int s = blockIdx.x, tid = threadIdx.x;
    __shared__ float wc[1024];
    __shared__ float red[2][4];

    const float4* b4 = (const float4*)(births + (size_t)s * 2048);
    const float4* d4 = (const float4*)(deaths + (size_t)s * 2048);
    float mnx = 3e38f, mny = 3e38f, mxx = -3e38f, mxy = -3e38f;
    #pragma unroll
    for (int k = 0; k < 4; ++k) {
        const float4 f = b4[tid + 128 * k];
        const float4 g = d4[tid + 128 * k];
        mnx = fminf(mnx, fminf(fminf(f.x, f.z), fminf(g.x, g.z)));
        mxx = fmaxf(mxx, fmaxf(fmaxf(f.x, f.z), fmaxf(g.x, g.z)));
        mny = fminf(mny, fminf(fminf(f.y, f.w), fminf(g.y, g.w)));
        mxy = fmaxf(mxy, fmaxf(fmaxf(f.y, f.w), fmaxf(g.y, g.w)));
        const int c = 2 * (tid + 128 * k);
        wc[c]     = fmaxf(fabsf(g.x - f.x), fabsf(g.y - f.y));
        wc[c + 1] = fmaxf(fabsf(g.z - f.z), fabsf(g.w - f.w));
    }
    #pragma unroll
    for (int off = 32; off > 0; off >>= 1) {
        mnx = fminf(mnx, __shfl_down(mnx, off));
        mny = fminf(mny, __shfl_down(mny, off));
        mxx = fmaxf(mxx, __shfl_down(mxx, off));
        mxy = fmaxf(mxy, __shfl_down(mxy, off));
    }
    const int wave = tid >> 6, lane = tid & 63;
    if (lane == 0) { red[wave][0] = mnx; red[wave][1] = mny; red[wave][2] = mxx; red[wave][3] = mxy; }
    __syncthreads();

    if (tid == 0) {
        const float a = fminf(red[0][0], red[1][0]);
        const float b = fminf(red[0][1], red[1][1]);
        const float c = fmaxf(red[0][2], red[1][2]);
        const float d = fmaxf(red[0][3], red[1][3]);
        const float mgx = 0.1f * (c - a), mgy = 0.1f * (d - b);
        float* w = ws + (size_t)s * WS_STRIDE;
        w[0] = a - mgx; w[1] = b - mgy; w[2] = c + mgx; w[3] = d + mgy;
    }
    if (tid < NI) {  // deterministic serial sum of 32 per-corner weights
        float ssum = 0.f;
        #pragma unroll
        for (int k = 0; k < 32; ++k) ssum += wc[tid * 32 + k];
        const float w = ssum * (1.0f / 32.0f);
        ws[(size_t)s * WS_STRIDE + 8 + tid] = w * w;
    }
    // zero this sample's output slice (kernel-node zeroing: graph-replay-safe)
    #pragma unroll
    for (int k = 0; k < 8; ++k) {
        const int g = tid + 128 * k;
        if (g < GPTS) out[(size_t)s * GPTS + g] = 0.f;
    }
}

// 8 rows updated per corner-component; named scalars only.
#define ROW8(M, Yc, P) \
    M##0 = fminf(M##0, fmaf(Yc, gy0, P)); \
    M##1 = fminf(M##1, fmaf(Yc, gy1, P)); \
    M##2 = fminf(M##2, fmaf(Yc, gy2, P)); \
    M##3 = fminf(M##3, fmaf(Yc, gy3, P)); \
    M##4 = fminf(M##4, fmaf(Yc, gy4, P)); \
    M##5 = fminf(M##5, fmaf(Yc, gy5, P)); \
    M##6 = fminf(M##6, fmaf(Yc, gy6, P)); \
    M##7 = fminf(M##7, fmaf(Yc, gy7, P));

#define CORN4(M, Xv, Yv, Rv) \
    { const float p = fmaf(Xv.x, gx, Rv.x); ROW8(M, Yv.x, p) } \
    { const float p = fmaf(Xv.y, gx, Rv.y); ROW8(M, Yv.y, p) } \
    { const float p = fmaf(Xv.z, gx, Rv.z); ROW8(M, Yv.z, p) } \
    { const float p = fmaf(Xv.w, gx, Rv.w); ROW8(M, Yv.w, p) }

__global__ __launch_bounds__(128, 4) void pimg_kernel(
    const float* __restrict__ births, const float* __restrict__ deaths,
    float* __restrict__ out, const float* __restrict__ ws)
{
    const int bid = blockIdx.x;
    const int s   = bid >> 4;
    const int i0  = (bid & 15) * 2;
    const int tid = threadIdx.x;

    __shared__ __align__(16) float Bqx[64], Bqy[64], Br[64];
    __shared__ __align__(16) float Dqx[64], Dqy[64], Dr[64];

    // corner transform for this block's 2 intervals (threads 0..63)
    if (tid < 64) {
        const size_t base = (size_t)s * 1024 + (size_t)i0 * 32 + tid;
        const float2 pb = ((const float2*)births)[base];
        Bqx[tid] = -2.f * pb.x; Bqy[tid] = -2.f * pb.y; Br[tid] = pb.x * pb.x + pb.y * pb.y;
        const float2 pd = ((const float2*)deaths)[base];
        Dqx[tid] = -2.f * pd.x; Dqy[tid] = -2.f * pd.y; Dr[tid] = pd.x * pd.x + pd.y * pd.y;
    }

    // box + weights from ws: s is block-uniform -> scalar loads
    const float* wsp = ws + (size_t)s * WS_STRIDE;
    const float lox = wsp[0], loy = wsp[1];
    const float sx  = (wsp[2] - lox) * INV29;
    const float sy  = (wsp[3] - loy) * INV29;
    const float w2a = wsp[8 + i0];
    const float w2b = wsp[8 + i0 + 1];

    __syncthreads();

    // thread -> (column ix, row-octet h: rows 8h..8h+7). tid>=120 computes
    // garbage (h=4) and skips the stores; no early return, no more barriers.
    const int ix = tid % 30;
    const int h  = tid / 30;

    const float gx  = fmaf((float)ix, sx, lox);
    const float gy0 = fmaf((float)(8 * h + 0), sy, loy);
    const float gy1 = fmaf((float)(8 * h + 1), sy, loy);
    const float gy2 = fmaf((float)(8 * h + 2), sy, loy);
    const float gy3 = fmaf((float)(8 * h + 3), sy, loy);
    const float gy4 = fmaf((float)(8 * h + 4), sy, loy);
    const float gy5 = fmaf((float)(8 * h + 5), sy, loy);
    const float gy6 = fmaf((float)(8 * h + 6), sy, loy);
    const float gy7 = fmaf((float)(8 * h + 7), sy, loy);

    float acc0 = 0.f, acc1 = 0.f, acc2 = 0.f, acc3 = 0.f;
    float acc4 = 0.f, acc5 = 0.f, acc6 = 0.f, acc7 = 0.f;

    #pragma unroll 1
    for (int il = 0; il < 2; ++il) {
        const float4* BX = (const float4*)Bqx + il * 8;
        const float4* BY = (const float4*)Bqy + il * 8;
        const float4* BR = (const float4*)Br  + il * 8;
        const float4* DX = (const float4*)Dqx + il * 8;
        const float4* DY = (const float4*)Dqy + il * 8;
        const float4* DR = (const float4*)Dr  + il * 8;

        float mb0 = 3e38f, mb1 = 3e38f, mb2 = 3e38f, mb3 = 3e38f;
        float mb4 = 3e38f, mb5 = 3e38f, mb6 = 3e38f, mb7 = 3e38f;
        float md0 = 3e38f, md1 = 3e38f, md2 = 3e38f, md3 = 3e38f;
        float md4 = 3e38f, md5 = 3e38f, md6 = 3e38f, md7 = 3e38f;

        #pragma unroll
        for (int q = 0; q < 8; ++q) {
            const float4 X = BX[q], Y = BY[q], R = BR[q];
            CORN4(mb, X, Y, R)
        }
        #pragma unroll
        for (int q = 0; q < 8; ++q) {
            const float4 X = DX[q], Y = DY[q], R = DR[q];
            CORN4(md, X, Y, R)
        }

        const float w2  = il ? w2b : w2a;
        const float gxs = gx * gx;
        {
            const float t0 = fmaxf(mb0, md0) + fmaf(gy0, gy0, gxs);
            const float t1 = fmaxf(mb1, md1) + fmaf(gy1, gy1, gxs);
            const float t2 = fmaxf(mb2, md2) + fmaf(gy2, gy2, gxs);
            const float t3 = fmaxf(mb3, md3) + fmaf(gy3, gy3, gxs);
            const float t4 = fmaxf(mb4, md4) + fmaf(gy4, gy4, gxs);
            const float t5 = fmaxf(mb5, md5) + fmaf(gy5, gy5, gxs);
            const float t6 = fmaxf(mb6, md6) + fmaf(gy6, gy6, gxs);
            const float t7 = fmaxf(mb7, md7) + fmaf(gy7, gy7, gxs);
            acc0 = fmaf(w2, __expf(-200.0f * t0), acc0);
            acc1 = fmaf(w2, __expf(-200.0f * t1), acc1);
            acc2 = fmaf(w2, __expf(-200.0f * t2), acc2);
            acc3 = fmaf(w2, __expf(-200.0f * t3), acc3);
            acc4 = fmaf(w2, __expf(-200.0f * t4), acc4);
            acc5 = fmaf(w2, __expf(-200.0f * t5), acc5);
            acc6 = fmaf(w2, __expf(-200.0f * t6), acc6);
            acc7 = fmaf(w2, __expf(-200.0f * t7), acc7);
        }
    }

    if (tid < 120) {
        float* op = out + (size_t)s * GPTS + ix * RES + 8 * h;
        const int base = 8 * h;  // rows base..base+7; mask rows >= 30 (h=3 tail)
        if (base + 0 < RES) atomicAdd(&op[0], acc0);
        if (base + 1 < RES) atomicAdd(&op[1], acc1);
        if (base + 2 < RES) atomicAdd(&op[2], acc2);
        if (base + 3 < RES) atomicAdd(&op[3], acc3);
        if (base + 4 < RES) atomicAdd(&op[4], acc4);
        if (base + 5 < RES) atomicAdd(&op[5], acc5);
        if (base + 6 < RES) atomicAdd(&op[6], acc6);
        if (base + 7 < RES) atomicAdd(&op[7], acc7);
    }
}

extern "C" void kernel_launch(void* const* d_in, const int* in_sizes, int n_in,
                              void* d_out, int out_size, void* d_ws, size_t ws_size,
                              hipStream_t stream) {
    const float* births = (const float*)d_in[0];
    const float* deaths = (const float*)d_in[1];
    float* out = (float*)d_out;
    float* ws  = (float*)d_ws;

    prep_kernel<<<NS, 128, 0, stream>>>(births, deaths, out, ws);
    pimg_kernel<<<NS * 16, 128, 0, stream>>>(births, deaths, out, ws);
}

// Round 5
// 87.274 us; speedup vs baseline: 2.7340x; 2.7340x over previous
//
#include <hip/hip_runtime.h>

// Persistence-image kernel, MI355X — R5: R1's proven register envelope +
// column-factorization + prep hoist.
// S=128, I=32 intervals, C=32 corners, R=30 -> G=900.
// img[s,g] = sum_i w_i^2 * exp(-200 * max(min_c |g-b_ic|^2, min_c |g-d_ic|^2))
// |g-p|^2 = (r_c + qx_c*gx + qy_c*gy) + |g|^2, qx=-2px, qy=-2py, r=|p|^2.
//
// Empirical rule from R2-R4: the compiler will NOT allocate >64 VGPRs here
// (R0:64, R3:40, R4:64) and anything whose peak live set exceeds ~45 floats
// spills catastrophically (R4: 192MB FETCH + 429MB WRITE scratch, VALU 7%).
// R5 therefore keeps R1's exact structure (4096 blocks x 128 thr, mb[4]/md[4]/
// acc[4] const-indexed arrays, (128,8) bounds) and changes ONLY:
//  - thread's 4 points now share ONE column (gx scalar, 4 consecutive rows):
//    per corner component p=fma(qx,gx,r) hoisted once, rows cost fma+min
//    -> 9 ops / 4 evals vs 12 (-23% inner VALU), live set SMALLER than R1.
//  - bbox/w2 hoisted to prep_kernel (verified 3 rounds): removes 16KB
//    redundant load + shfl tree + serial w-sum + barrier from every block.
// Block (s, i-pair, gh-half): gh half = 15 cols x 30 rows; thread t ->
// col t>>3 (15 active of 16), row-quad t&7 (rows 4rq..4rq+3, 30-31 masked).

#define RES 30
#define GPTS 900
#define NS 128
#define NI 32
#define INV29 (1.0f / 29.0f)
#define WS_STRIDE 40  // floats per sample: [0..3]=box lo/hi, [8..39]=w2[i]

__global__ __launch_bounds__(128) void prep_kernel(
    const float* __restrict__ births, const float* __restrict__ deaths,
    float* __restrict__ out, float* __restrict__ ws)
{
    const int s = blockIdx.x, tid = threadIdx.x;
    __shared__ float wc[1024];
    __shared__ float red[2][4];

    const float4* b4 = (const float4*)(births + (size_t)s * 2048);
    const float4* d4 = (const float4*)(deaths + (size_t)s * 2048);
    float mnx = 3e38f, mny = 3e38f, mxx = -3e38f, mxy = -3e38f;
    #pragma unroll
    for (int k = 0; k < 4; ++k) {
        const float4 f = b4[tid + 128 * k];
        const float4 g = d4[tid + 128 * k];
        mnx = fminf(mnx, fminf(fminf(f.x, f.z), fminf(g.x, g.z)));
        mxx = fmaxf(mxx, fmaxf(fmaxf(f.x, f.z), fmaxf(g.x, g.z)));
        mny = fminf(mny, fminf(fminf(f.y, f.w), fminf(g.y, g.w)));
        mxy = fmaxf(mxy, fmaxf(fmaxf(f.y, f.w), fmaxf(g.y, g.w)));
        const int c = 2 * (tid + 128 * k);
        wc[c]     = fmaxf(fabsf(g.x - f.x), fabsf(g.y - f.y));
        wc[c + 1] = fmaxf(fabsf(g.z - f.z), fabsf(g.w - f.w));
    }
    #pragma unroll
    for (int off = 32; off > 0; off >>= 1) {
        mnx = fminf(mnx, __shfl_down(mnx, off));
        mny = fminf(mny, __shfl_down(mny, off));
        mxx = fmaxf(mxx, __shfl_down(mxx, off));
        mxy = fmaxf(mxy, __shfl_down(mxy, off));
    }
    const int wave = tid >> 6, lane = tid & 63;
    if (lane == 0) { red[wave][0] = mnx; red[wave][1] = mny; red[wave][2] = mxx; red[wave][3] = mxy; }
    __syncthreads();

    if (tid == 0) {
        const float a = fminf(red[0][0], red[1][0]);
        const float b = fminf(red[0][1], red[1][1]);
        const float c = fmaxf(red[0][2], red[1][2]);
        const float d = fmaxf(red[0][3], red[1][3]);
        const float mgx = 0.1f * (c - a), mgy = 0.1f * (d - b);
        float* w = ws + (size_t)s * WS_STRIDE;
        w[0] = a - mgx; w[1] = b - mgy; w[2] = c + mgx; w[3] = d + mgy;
    }
    if (tid < NI) {  // deterministic serial sum of 32 per-corner weights
        float ssum = 0.f;
        #pragma unroll
        for (int k = 0; k < 32; ++k) ssum += wc[tid * 32 + k];
        const float w = ssum * (1.0f / 32.0f);
        ws[(size_t)s * WS_STRIDE + 8 + tid] = w * w;
    }
    // zero this sample's output slice (kernel-node zeroing: graph-replay-safe)
    #pragma unroll
    for (int k = 0; k < 8; ++k) {
        const int g = tid + 128 * k;
        if (g < GPTS) out[(size_t)s * GPTS + g] = 0.f;
    }
}

__global__ __launch_bounds__(128, 8) void pimg_kernel(
    const float* __restrict__ births, const float* __restrict__ deaths,
    float* __restrict__ out, const float* __restrict__ ws)
{
    const int bid = blockIdx.x;
    const int s   = bid >> 5;
    const int i0  = ((bid >> 1) & 15) * 2;
    const int gh  = bid & 1;
    const int tid = threadIdx.x;

    __shared__ __align__(16) float Bqx[64], Bqy[64], Br[64];
    __shared__ __align__(16) float Dqx[64], Dqy[64], Dr[64];

    // corner transform for this block's 2 intervals (threads 0..63)
    if (tid < 64) {
        const size_t base = (size_t)s * 1024 + (size_t)i0 * 32 + tid;
        const float2 pb = ((const float2*)births)[base];
        Bqx[tid] = -2.f * pb.x; Bqy[tid] = -2.f * pb.y; Br[tid] = pb.x * pb.x + pb.y * pb.y;
        const float2 pd = ((const float2*)deaths)[base];
        Dqx[tid] = -2.f * pd.x; Dqy[tid] = -2.f * pd.y; Dr[tid] = pd.x * pd.x + pd.y * pd.y;
    }

    // box + weights from ws (s uniform -> scalar loads)
    const float* wsp = ws + (size_t)s * WS_STRIDE;
    const float lox = wsp[0], loy = wsp[1];
    const float sx  = (wsp[2] - lox) * INV29;
    const float sy  = (wsp[3] - loy) * INV29;
    const float w2a = wsp[8 + i0];
    const float w2b = wsp[8 + i0 + 1];

    __syncthreads();

    // thread -> (column c of this gh-half, row-quad rq): pure shift/and.
    // c==15 lanes and rows>=30 compute garbage, masked at the atomics.
    const int c   = tid >> 3;          // 0..15
    const int rq  = tid & 7;           // 0..7
    const int ix  = gh * 15 + c;
    const int iy0 = rq * 4;            // 0,4,...,28

    const float gx  = fmaf((float)ix, sx, lox);
    float gy[4], mb[4], md[4], acc[4];
    #pragma unroll
    for (int j = 0; j < 4; ++j) {
        gy[j]  = fmaf((float)(iy0 + j), sy, loy);
        acc[j] = 0.f;
    }

    const float4* Bqx4 = (const float4*)Bqx;
    const float4* Bqy4 = (const float4*)Bqy;
    const float4* Br4  = (const float4*)Br;
    const float4* Dqx4 = (const float4*)Dqx;
    const float4* Dqy4 = (const float4*)Dqy;
    const float4* Dr4  = (const float4*)Dr;

    #pragma unroll 1
    for (int il = 0; il < 2; ++il) {
        #pragma unroll
        for (int j = 0; j < 4; ++j) { mb[j] = 3e38f; md[j] = 3e38f; }

        #pragma unroll
        for (int q = 0; q < 8; ++q) {
            const float4 X  = Bqx4[il * 8 + q];
            const float4 Y  = Bqy4[il * 8 + q];
            const float4 Rr = Br4[il * 8 + q];
            {
                const float p = fmaf(X.x, gx, Rr.x);
                #pragma unroll
                for (int j = 0; j < 4; ++j) mb[j] = fminf(mb[j], fmaf(Y.x, gy[j], p));
            }
            {
                const float p = fmaf(X.y, gx, Rr.y);
                #pragma unroll
                for (int j = 0; j < 4; ++j) mb[j] = fminf(mb[j], fmaf(Y.y, gy[j], p));
            }
            {
                const float p = fmaf(X.z, gx, Rr.z);
                #pragma unroll
                for (int j = 0; j < 4; ++j) mb[j] = fminf(mb[j], fmaf(Y.z, gy[j], p));
            }
            {
                const float p = fmaf(X.w, gx, Rr.w);
                #pragma unroll
                for (int j = 0; j < 4; ++j) mb[j] = fminf(mb[j], fmaf(Y.w, gy[j], p));
            }
        }
        #pragma unroll
        for (int q = 0; q < 8; ++q) {
            const float4 X  = Dqx4[il * 8 + q];
            const float4 Y  = Dqy4[il * 8 + q];
            const float4 Rr = Dr4[il * 8 + q];
            {
                const float p = fmaf(X.x, gx, Rr.x);
                #pragma unroll
                for (int j = 0; j < 4; ++j) md[j] = fminf(md[j], fmaf(Y.x, gy[j], p));
            }
            {
                const float p = fmaf(X.y, gx, Rr.y);
                #pragma unroll
                for (int j = 0; j < 4; ++j) md[j] = fminf(md[j], fmaf(Y.y, gy[j], p));
            }
            {
                const float p = fmaf(X.z, gx, Rr.z);
                #pragma unroll
                for (int j = 0; j < 4; ++j) md[j] = fminf(md[j], fmaf(Y.z, gy[j], p));
            }
            {
                const float p = fmaf(X.w, gx, Rr.w);
                #pragma unroll
                for (int j = 0; j < 4; ++j) md[j] = fminf(md[j], fmaf(Y.w, gy[j], p));
            }
        }

        const float w2  = il ? w2b : w2a;
        const float gxs = gx * gx;
        #pragma unroll
        for (int j = 0; j < 4; ++j) {
            const float t = fmaxf(mb[j], md[j]) + fmaf(gy[j], gy[j], gxs);
            acc[j] = fmaf(w2, __expf(-200.0f * t), acc[j]);
        }
    }

    if (c < 15) {
        float* op = out + (size_t)s * GPTS + ix * RES + iy0;
        #pragma unroll
        for (int j = 0; j < 4; ++j) {
            if (iy0 + j < RES) atomicAdd(&op[j], acc[j]);
        }
    }
}

extern "C" void kernel_launch(void* const* d_in, const int* in_sizes, int n_in,
                              void* d_out, int out_size, void* d_ws, size_t ws_size,
                              hipStream_t stream) {
    const float* births = (const float*)d_in[0];
    const float* deaths = (const float*)d_in[1];
    float* out = (float*)d_out;
    float* ws  = (float*)d_ws;

    prep_kernel<<<NS, 128, 0, stream>>>(births, deaths, out, ws);
    pimg_kernel<<<NS * 32, 128, 0, stream>>>(births, deaths, out, ws);
}